// Round 15
// baseline (67.149 us; speedup 1.0000x reference)
//
#include <hip/hip_runtime.h>
#include <hip/hip_bf16.h>

#define UNITS 64
#define IFEAT 256
#define OFEAT 256

typedef __attribute__((ext_vector_type(8))) short v8s;   // 8 bf16 (4 VGPRs)
typedef __attribute__((ext_vector_type(4))) float v4f;   // MFMA acc / global f32x4

// pack 2 floats -> u32 of 2 bf16 (RNE) — compiler emits v_cvt_pk_bf16_f32
static __device__ __forceinline__ unsigned int pk2(float a, float b) {
    union { __hip_bfloat162 h; unsigned int u; } c;
    c.h = __float22bfloat162_rn(float2{a, b});
    return c.u;
}
static __device__ __forceinline__ v8s pk8(const float* r) {
    union { uint4 u4; v8s s8; } cv;
    cv.u4.x = pk2(r[0], r[1]);
    cv.u4.y = pk2(r[2], r[3]);
    cv.u4.z = pk2(r[4], r[5]);
    cv.u4.w = pk2(r[6], r[7]);
    return cv.s8;
}

static __device__ __forceinline__ float sigmoid_f(float x) {
    return 1.0f / (1.0f + __expf(-x));
}
static __device__ __forceinline__ float tanh_f(float x) {
    float ax = fabsf(x);
    float e = __expf(-2.0f * ax);
    float t = (1.0f - e) / (1.0f + e);
    return copysignf(t, x);
}

// ---------------------------------------------------------------------------
// Fused GRU, tuned for 4 RESIDENT waves/SIMD (the regime R4-R14 never hit):
// BM=128, BN=32, 256 threads = 4 waves (2m x 2n), wave tile 64x16.
// acc[3][4](48) + acch[3](12) + rb[3][8](24) + bf(4) + addr ~= 125 unified
// regs -> __launch_bounds__(256,4) caps at 128, 4 waves/SIMD resident.
// A (x) tile HALF-K in LDS (16kq x 128rows = 32KB, rotated conflict-free):
// 4 blocks/CU resident (133KB); two passes with mid-kernel restage (4-load
// chunks keep transient regs at 16; the bubble is covered by the other 3
// independent blocks). B: 48-slot (16 steps x 3 gates) stream, depth-3
// rotating reg buffers (2-slot lookahead, static indices via full unroll),
// ZERO in-loop barriers. h-terms via broadcast-Ht MFMA (R12-proven).
// Grid 1024 = 64u x 2mb x 8nb, XCD-swizzled (unit's 16 blocks share W/x in
// their XCD L2). W HBM x1, L2 x2; x L2 x8 (small).
// ---------------------------------------------------------------------------
__global__ __launch_bounds__(256, 4) void gru_fused(
    const float* __restrict__ x,
    const float* __restrict__ wir,
    const float* __restrict__ wiz,
    const float* __restrict__ win,
    const float* __restrict__ whr,
    const float* __restrict__ whz,
    const float* __restrict__ whn,
    const float* __restrict__ hinit,
    float* __restrict__ out) {
    __shared__ unsigned short As[16][128][8];        // [kqL][row'][j]  32 KB
    __shared__ unsigned short Ht[32][8];             // h broadcast    512 B

    const int bid = blockIdx.x;
    // XCD swizzle: xcd = bid&7 owns units [xcd*8, xcd*8+8); 16 blocks/unit.
    const int loc = bid >> 3;                  // 0..127 within XCD
    const int u   = (bid & 7) * 8 + (loc >> 4);
    const int rem = loc & 15;
    const int b0  = (rem >> 3) * 128;          // batch tile 0..1
    const int o0  = (rem & 7) * 32;            // out-feature tile 0..7

    const int t    = threadIdx.x;
    const int lane = t & 63;
    const int wv   = t >> 6;                   // 4 waves: 2m x 2n
    const int wm   = wv >> 1;                  // 0/1 (64-row halves)
    const int wn   = wv & 1;                   // 0/1 (16-col slices)
    const int lg   = lane >> 4;                // k-group 0..3
    const int lr   = lane & 15;

    const float* WX[3] = {wir, wiz, win};
    const float* WH[3] = {whr, whz, whn};

    const int col = o0 + wn * 16 + lr;
    const size_t wbase = (size_t)u * (IFEAT * OFEAT) + col;

    // ---- A staging (half-K), 4-load chunks (16 transient regs) ----
    const int h32  = t & 31;                   // k-quad within half: 4 floats
    const int rgrp = t >> 5;                   // row group 0..7
    const int kqL  = h32 >> 1;
    const int j0   = (h32 & 1) * 4;
    auto stageA = [&](int pass) {
#pragma unroll
        for (int c = 0; c < 4; ++c) {
            v4f q[4];
#pragma unroll
            for (int i = 0; i < 4; ++i) {
                const int row = rgrp * 16 + c * 4 + i;
                q[i] = *(const v4f*)(x + (size_t)(b0 + row) * (UNITS * IFEAT)
                                       + u * IFEAT + pass * 128 + h32 * 4);
            }
#pragma unroll
            for (int i = 0; i < 4; ++i) {
                const int row = rgrp * 16 + c * 4 + i;
                uint2 w;
                w.x = pk2(q[i][0], q[i][1]);
                w.y = pk2(q[i][2], q[i][3]);
                *(uint2*)&As[kqL][(row + kqL) & 127][j0] = w;
            }
        }
    };

    // slot s (0..47): pass=s/24, p=(s%24)/6, ph=(s%6)/3, g=s%3
    float rb[3][8];                            // depth-3 rotating B buffers
    auto loadB = [&](float* dst, int slot) {
        const int pass = slot / 24, r24 = slot % 24;
        const int p = r24 / 6, ph = (r24 % 6) / 3, g = r24 % 3;
        const float* w = ph ? WH[g] : WX[g];
        const int k0 = (pass * 4 + p) * 32 + lg * 8;
        const float* ptr = w + wbase + (size_t)k0 * OFEAT;
#pragma unroll
        for (int j = 0; j < 8; ++j) dst[j] = ptr[j * OFEAT];
    };

    v4f acc[3][4];                             // [gate][mi] x-part
    v4f acch[3];                               // [gate]     h-part (bcast)
#pragma unroll
    for (int g = 0; g < 3; ++g) {
#pragma unroll
        for (int mi = 0; mi < 4; ++mi)
            acc[g][mi] = (v4f){0.f, 0.f, 0.f, 0.f};
        acch[g] = (v4f){0.f, 0.f, 0.f, 0.f};
    }

    // ---- prologue ----
    stageA(0);
    if (t < 32) {
        const float* hp = hinit + u * IFEAT + t * 8;
        v4f q0 = *(const v4f*)hp;
        v4f q1 = *(const v4f*)(hp + 4);
        uint4 w;
        w.x = pk2(q0[0], q0[1]);
        w.y = pk2(q0[2], q0[3]);
        w.z = pk2(q1[0], q1[1]);
        w.w = pk2(q1[2], q1[3]);
        *(uint4*)&Ht[t][0] = w;
    }
    loadB(rb[0], 0);
    loadB(rb[1], 1);
    __syncthreads();

    // ---- 48-slot stream, zero barriers except the pass-1 restage ----
#pragma unroll
    for (int pass = 0; pass < 2; ++pass) {
        if (pass == 1) {
            __syncthreads();                   // pass-0 x-reads done
            stageA(1);                         // restage other K-half
            __syncthreads();                   // writes visible
        }
#pragma unroll
        for (int p = 0; p < 4; ++p) {
#pragma unroll
            for (int ph = 0; ph < 2; ++ph) {
#pragma unroll
                for (int g = 0; g < 3; ++g) {
                    const int slot = pass * 24 + p * 6 + ph * 3 + g;
                    v8s bfv = pk8(rb[slot % 3]);
                    if (slot < 46) loadB(rb[(slot + 2) % 3], slot + 2);
                    if (ph == 0) {
                        const int kq = p * 4 + lg;
#pragma unroll
                        for (int mi = 0; mi < 4; ++mi) {
                            v8s a = *(const v8s*)
                                &As[kq][((wm * 64 + mi * 16 + lr) + kq) & 127][0];
                            acc[g][mi] = __builtin_amdgcn_mfma_f32_16x16x32_bf16(
                                a, bfv, acc[g][mi], 0, 0, 0);
                        }
                    } else {
                        v8s a0h = *(const v8s*)&Ht[(pass * 4 + p) * 4 + lg][0];
                        acch[g] = __builtin_amdgcn_mfma_f32_16x16x32_bf16(
                            a0h, bfv, acch[g], 0, 0, 0);
                    }
                }
            }
        }
    }

    // ---- epilogue: GRU combine ----
    // C layout: col = lane&15, row = (lane>>4)*4 + reg; acch rows identical
    const float h0v = hinit[u * OFEAT + col];
    const float hr = acch[0][0];
    const float hz = acch[1][0];
    const float hn = acch[2][0];
#pragma unroll
    for (int mi = 0; mi < 4; ++mi) {
#pragma unroll
        for (int jj = 0; jj < 4; ++jj) {
            const int row = b0 + wm * 64 + mi * 16 + lg * 4 + jj;
            const float r = sigmoid_f(acc[0][mi][jj] + hr);
            const float z = sigmoid_f(acc[1][mi][jj] + hz);
            const float n = tanh_f(acc[2][mi][jj] + r * hn);
            out[(size_t)row * (UNITS * OFEAT) + u * OFEAT + col] =
                (1.0f - z) * n + z * h0v;
        }
    }
}

extern "C" void kernel_launch(void* const* d_in, const int* in_sizes, int n_in,
                              void* d_out, int out_size, void* d_ws, size_t ws_size,
                              hipStream_t stream) {
    const float* x     = (const float*)d_in[0];
    const float* w_ir  = (const float*)d_in[1];
    const float* w_iz  = (const float*)d_in[2];
    const float* w_in  = (const float*)d_in[3];
    const float* w_hr  = (const float*)d_in[4];
    const float* w_hz  = (const float*)d_in[5];
    const float* w_hn  = (const float*)d_in[6];
    const float* hinit = (const float*)d_in[7];
    float* out = (float*)d_out;

    gru_fused<<<dim3(1024), dim3(256), 0, stream>>>(
        x, w_ir, w_iz, w_in, w_hr, w_hz, w_hn, hinit, out);
}

// Round 16
// 34.781 us; speedup vs baseline: 1.9306x; 1.9306x over previous
//
#include <hip/hip_runtime.h>
#include <hip/hip_bf16.h>

#define UNITS 64
#define IFEAT 256
#define OFEAT 256

typedef __attribute__((ext_vector_type(8))) short v8s;   // 8 bf16 (4 VGPRs)
typedef __attribute__((ext_vector_type(4))) float v4f;   // MFMA acc / global f32x4

// pack 2 floats -> u32 of 2 bf16 (RNE) — compiler emits v_cvt_pk_bf16_f32
static __device__ __forceinline__ unsigned int pk2(float a, float b) {
    union { __hip_bfloat162 h; unsigned int u; } c;
    c.h = __float22bfloat162_rn(float2{a, b});
    return c.u;
}
static __device__ __forceinline__ v8s pk8(const float* r) {
    union { uint4 u4; v8s s8; } cv;
    cv.u4.x = pk2(r[0], r[1]);
    cv.u4.y = pk2(r[2], r[3]);
    cv.u4.z = pk2(r[4], r[5]);
    cv.u4.w = pk2(r[6], r[7]);
    return cv.s8;
}

static __device__ __forceinline__ float sigmoid_f(float x) {
    return 1.0f / (1.0f + __expf(-x));
}
static __device__ __forceinline__ float tanh_f(float x) {
    float ax = fabsf(x);
    float e = __expf(-2.0f * ax);
    float t = (1.0f - e) / (1.0f + e);
    return copysignf(t, x);
}

// ---------------------------------------------------------------------------
// Fused GRU. ONE structural change vs R12 (best, 32.5us): W is staged by
// global_load_lds DMA (f32, width=16) instead of per-thread scalar loads.
//   - VMEM instrs for W: 24 -> 3 per thread-step (8x down)
//   - staging registers eliminated -> no spill risk (killed R9/R10/R15)
//   - cvt f32->bf16 moves to frag-read (12 pk2/step, same aggregate VALU)
// BM=128, BN=64, BK=32, 512 thr = 8 waves (2m x 4n), wave tile 64x16.
// A (x): rotated bf16 LDS tile, HALF-K (16kq x 128 = 32KB), restaged once.
// B (W): Bf[2][3][32][64] f32 = 48KB, double-buffered, one barrier/step
// (m97 pattern). LDS = 80KB exactly -> 2 blocks/CU, 4 waves/SIMD resident.
// Bank swizzle: LDS col-group XORed via PRE-SWIZZLED GLOBAL source (m104:
// global_load_lds dest must stay linear); read applies the same XOR ->
// 2-way banks (free). h-phase: 8 steps, broadcast-Ht A, 3 MFMA/step into
// acch[3] (rows identical, R12-proven); Ht overlays As after the x-phase.
// Grid 512 = 64u x 2mb x 4nb, XCD-swizzled (unit's 8 blocks on one XCD).
// ---------------------------------------------------------------------------
__global__ __launch_bounds__(512, 4) void gru_fused(
    const float* __restrict__ x,
    const float* __restrict__ wir,
    const float* __restrict__ wiz,
    const float* __restrict__ win,
    const float* __restrict__ whr,
    const float* __restrict__ whz,
    const float* __restrict__ whn,
    const float* __restrict__ hinit,
    float* __restrict__ out) {
    __shared__ unsigned short As[16][128][8];    // [kqL][row'][j] bf16  32 KB
    __shared__ float Bf[2][3][32][64];           // [buf][g][k][col] f32 48 KB

    const int bid = blockIdx.x;
    // XCD swizzle: xcd = bid&7 owns units [xcd*8, xcd*8+8); 8 blocks/unit.
    const int loc = bid >> 3;                  // 0..63 within XCD
    const int u   = (bid & 7) * 8 + (loc >> 3);
    const int rem = loc & 7;
    const int b0  = (rem >> 2) * 128;          // batch tile 0..1
    const int o0  = (rem & 3) * 64;            // out-feature tile 0..3

    const int t    = threadIdx.x;
    const int lane = t & 63;
    const int wv   = t >> 6;                   // 8 waves: 2m x 4n
    const int wm   = wv >> 2;                  // 0/1  (64-row halves)
    const int wn   = wv & 3;                   // 0..3 (16-col slices)
    const int lg   = lane >> 4;                // k-group 0..3
    const int lr   = lane & 15;

    const float* WX[3] = {wir, wiz, win};
    const float* WH[3] = {whr, whz, whn};

    // ---- B staging via global_load_lds: thread t owns granule t per gate.
    // LDS linear dest = Bf[buf][g] + t*16B  (wave-uniform base + lane*16 ✓).
    // Global col-group PRE-SWIZZLED so reads can XOR-deswizzle (bank fix).
    const int brow  = t >> 4;                  // 0..31 (k row)
    const int bcolg = t & 15;                  // 16B col-granule
    const int bcolg_src = bcolg ^ (((brow >> 3) & 1) << 2);
    const size_t bgbase = (size_t)u * (IFEAT * OFEAT)
                        + (size_t)brow * OFEAT + o0 + bcolg_src * 4;

    auto stageB = [&](int buf, int sp) {       // sp = global step 0..15
        const float* const* W = (sp < 8) ? WX : WH;
        const size_t off = bgbase + (size_t)((sp & 7) * 32) * OFEAT;
#pragma unroll
        for (int g = 0; g < 3; ++g) {
            __builtin_amdgcn_global_load_lds(
                (const __attribute__((address_space(1))) void*)(W[g] + off),
                (__attribute__((address_space(3))) void*)(&Bf[buf][g][brow][bcolg * 4]),
                16, 0, 0);
        }
    };

    // ---- A (x) staging: rotated bf16 layout, half-K per pass ----
    auto stage_x = [&](int half) {
        const int kq8 = t & 15;
        const int r0  = t >> 4;                // 0..31
#pragma unroll
        for (int c = 0; c < 4; ++c) {
            const int row = r0 + 32 * c;
            const float* ap = x + (size_t)(b0 + row) * (UNITS * IFEAT)
                                + u * IFEAT + half * 128 + kq8 * 8;
            v4f q0 = *(const v4f*)ap;
            v4f q1 = *(const v4f*)(ap + 4);
            v8s av;
            union { uint4 u4; v8s s8; } cv;
            cv.u4.x = pk2(q0[0], q0[1]);
            cv.u4.y = pk2(q0[2], q0[3]);
            cv.u4.z = pk2(q1[0], q1[1]);
            cv.u4.w = pk2(q1[2], q1[3]);
            av = cv.s8;
            *(v8s*)&As[kq8][(row + kq8) & 127][0] = av;
        }
    };

    v4f acc[3][4];                             // [gate][mi] x-part
    v4f acch[3];                               // [gate]     h-part (bcast)
#pragma unroll
    for (int g = 0; g < 3; ++g) {
#pragma unroll
        for (int mi = 0; mi < 4; ++mi)
            acc[g][mi] = (v4f){0.f, 0.f, 0.f, 0.f};
        acch[g] = (v4f){0.f, 0.f, 0.f, 0.f};
    }

    // B-frag read: f32 from Bf (XOR-deswizzled col -> 2-way banks) + cvt
    const int bc = wn * 16 + lr;               // this lane's col
    auto bfrag = [&](int bb, int g) -> v8s {
        float bw[8];
        const int c = bc ^ ((lg & 1) << 4);
#pragma unroll
        for (int j = 0; j < 8; ++j) bw[j] = Bf[bb][g][lg * 8 + j][c];
        return pk8(bw);
    };

    // ---- prologue ----
    v4f hq0 = {0.f, 0.f, 0.f, 0.f}, hq1 = {0.f, 0.f, 0.f, 0.f};
    stageB(0, 0);
    stageB(1, 1);
    stage_x(0);
    if (t < 32) {                              // prefetch hinit into regs
        const float* hp = hinit + u * IFEAT + t * 8;
        hq0 = *(const v4f*)hp;
        hq1 = *(const v4f*)(hp + 4);
    }
    __syncthreads();                           // B0,B1 + As(half0) ready

    // ---- x-phase: steps 0..7 (K = 0..255 of x@W_i) ----
#pragma unroll
    for (int s = 0; s < 4; ++s) {
        const int bb  = s & 1;
        const int kqL = s * 4 + lg;
        v8s a[4];
#pragma unroll
        for (int mi = 0; mi < 4; ++mi)
            a[mi] = *(const v8s*)&As[kqL][((wm * 64 + mi * 16 + lr) + kqL) & 127][0];
#pragma unroll
        for (int g = 0; g < 3; ++g) {
            v8s bfv = bfrag(bb, g);
#pragma unroll
            for (int mi = 0; mi < 4; ++mi)
                acc[g][mi] = __builtin_amdgcn_mfma_f32_16x16x32_bf16(
                    a[mi], bfv, acc[g][mi], 0, 0, 0);
        }
        __syncthreads();
        stageB(bb, s + 2);
    }
    stage_x(1);                                // restage As with k=128..255
    __syncthreads();
#pragma unroll
    for (int s = 4; s < 8; ++s) {
        const int bb  = s & 1;
        const int kqL = (s - 4) * 4 + lg;
        v8s a[4];
#pragma unroll
        for (int mi = 0; mi < 4; ++mi)
            a[mi] = *(const v8s*)&As[kqL][((wm * 64 + mi * 16 + lr) + kqL) & 127][0];
#pragma unroll
        for (int g = 0; g < 3; ++g) {
            v8s bfv = bfrag(bb, g);
#pragma unroll
            for (int mi = 0; mi < 4; ++mi)
                acc[g][mi] = __builtin_amdgcn_mfma_f32_16x16x32_bf16(
                    a[mi], bfv, acc[g][mi], 0, 0, 0);
        }
        __syncthreads();
        stageB(bb, s + 2);                     // stages steps 6..9 (WH for 8,9)
    }

    // ---- Ht: overlay h bf16 into the (now unused) As region ----
    if (t < 32) {
        uint4 w;
        w.x = pk2(hq0[0], hq0[1]);
        w.y = pk2(hq0[2], hq0[3]);
        w.z = pk2(hq1[0], hq1[1]);
        w.w = pk2(hq1[2], hq1[3]);
        *((uint4*)&As[0][0][0] + t) = w;       // Ht[kq=t][j=0..7]
    }
    __syncthreads();
    const unsigned short* HtP = &As[0][0][0];

    // ---- h-phase: steps 8..15 (K = 0..255 of h@W_h, broadcast A) ----
#pragma unroll
    for (int s = 8; s < 16; ++s) {
        const int bb = s & 1;
        v8s a0h = *(const v8s*)(HtP + ((s - 8) * 4 + lg) * 8);
#pragma unroll
        for (int g = 0; g < 3; ++g) {
            v8s bfv = bfrag(bb, g);
            acch[g] = __builtin_amdgcn_mfma_f32_16x16x32_bf16(
                a0h, bfv, acch[g], 0, 0, 0);
        }
        __syncthreads();
        if (s < 14) stageB(bb, s + 2);
    }

    // ---- epilogue: GRU combine ----
    // C layout: col = lane&15, row = (lane>>4)*4 + reg; acch rows identical
    const int o = o0 + bc;
    const float h0v = hinit[u * OFEAT + o];
    const float hr = acch[0][0];
    const float hz = acch[1][0];
    const float hn = acch[2][0];
#pragma unroll
    for (int mi = 0; mi < 4; ++mi) {
#pragma unroll
        for (int jj = 0; jj < 4; ++jj) {
            const int row = b0 + wm * 64 + mi * 16 + lg * 4 + jj;
            const float r = sigmoid_f(acc[0][mi][jj] + hr);
            const float z = sigmoid_f(acc[1][mi][jj] + hz);
            const float n = tanh_f(acc[2][mi][jj] + r * hn);
            out[(size_t)row * (UNITS * OFEAT) + u * OFEAT + o] =
                (1.0f - z) * n + z * h0v;
        }
    }
}

extern "C" void kernel_launch(void* const* d_in, const int* in_sizes, int n_in,
                              void* d_out, int out_size, void* d_ws, size_t ws_size,
                              hipStream_t stream) {
    const float* x     = (const float*)d_in[0];
    const float* w_ir  = (const float*)d_in[1];
    const float* w_iz  = (const float*)d_in[2];
    const float* w_in  = (const float*)d_in[3];
    const float* w_hr  = (const float*)d_in[4];
    const float* w_hz  = (const float*)d_in[5];
    const float* w_hn  = (const float*)d_in[6];
    const float* hinit = (const float*)d_in[7];
    float* out = (float*)d_out;

    gru_fused<<<dim3(512), dim3(512), 0, stream>>>(
        x, w_ir, w_iz, w_in, w_hr, w_hz, w_hn, hinit, out);
}

// Round 17
// 31.818 us; speedup vs baseline: 2.1104x; 1.0931x over previous
//
#include <hip/hip_runtime.h>
#include <hip/hip_bf16.h>

#define UNITS 64
#define IFEAT 256
#define OFEAT 256

typedef __attribute__((ext_vector_type(8))) short v8s;   // 8 bf16 (4 VGPRs)
typedef __attribute__((ext_vector_type(4))) float v4f;   // MFMA acc / global f32x4

// pack 2 floats -> u32 of 2 bf16 (RNE) — compiler emits v_cvt_pk_bf16_f32
static __device__ __forceinline__ unsigned int pk2(float a, float b) {
    union { __hip_bfloat162 h; unsigned int u; } c;
    c.h = __float22bfloat162_rn(float2{a, b});
    return c.u;
}
static __device__ __forceinline__ v8s pk8(const float* r) {
    union { uint4 u4; v8s s8; } cv;
    cv.u4.x = pk2(r[0], r[1]);
    cv.u4.y = pk2(r[2], r[3]);
    cv.u4.z = pk2(r[4], r[5]);
    cv.u4.w = pk2(r[6], r[7]);
    return cv.s8;
}

static __device__ __forceinline__ float sigmoid_f(float x) {
    return 1.0f / (1.0f + __expf(-x));
}
static __device__ __forceinline__ float tanh_f(float x) {
    float ax = fabsf(x);
    float e = __expf(-2.0f * ax);
    float t = (1.0f - e) / (1.0f + e);
    return copysignf(t, x);
}

// ---------------------------------------------------------------------------
// Fused GRU = R12's proven 32.47us kernel (barrier-free, B-in-reg, 8 waves,
// wave tile 128x16, rotated full-K A tile) with TWO targeted changes:
//  1) 2-stage operand pipeline at constant register cost: f32 double-buffer
//     (rbFa/rbFb, 48) + bf16 operand queue (bfQa/bfQb, 24). Per step s:
//       issue loads(s+2) -> rbF[s&1]   (earliest point in step)
//       MFMA(s) from bfQ[s&1]          (operands cvt'd LAST step, no wait)
//       cvt(s+1): rbF[(s+1)&1] -> bfQ[(s+1)&1]  (vmcnt wait lands ~1.5-2
//                 step-times after issue vs R12's ~1 -> covers L2 latency)
//  2) h-phase: 3 MFMA/step into acch[3] (broadcast rows identical; added in
//     epilogue) instead of 17 -> saves 112 MFMAs/wave. (R12-proposal idea,
//     without R13's single-buffer regression.)
// Grid 256 = 64u x 2mb x 2nb (XCD-swizzled), 512 thr, 1 block/CU.
// Budget: acc 96 + acch 12 + rbF 48 + bfQ 24 + a-frags 32 + addr ~20 ≈ 232
// of 256 (2 waves/SIMD). WRITE_SIZE is the spill sentinel.
// ---------------------------------------------------------------------------
__global__ __launch_bounds__(512, 1) void gru_fused(
    const float* __restrict__ x,
    const float* __restrict__ wir,
    const float* __restrict__ wiz,
    const float* __restrict__ win,
    const float* __restrict__ whr,
    const float* __restrict__ whz,
    const float* __restrict__ whn,
    const float* __restrict__ hinit,
    float* __restrict__ out) {
    __shared__ unsigned short As[32][128][8];        // [kq][row'][j]   64 KB
    __shared__ unsigned short Ht[32][8];             // h broadcast    512 B

    const int bid = blockIdx.x;
    // XCD swizzle: xcd = bid&7 owns units [xcd*8, xcd*8+8); 4 blocks/unit.
    const int idx = bid >> 3;                  // 0..31 within XCD
    const int u   = (bid & 7) * 8 + (idx >> 2);
    const int rem = idx & 3;
    const int b0  = (rem >> 1) * 128;          // batch tile 0..1
    const int o0  = (rem & 1) * 128;           // out-feature tile 0..1

    const int t    = threadIdx.x;
    const int lane = t & 63;
    const int wv   = t >> 6;                   // 8 waves = 8 col-slices
    const int lg   = lane >> 4;                // k-group 0..3
    const int lr   = lane & 15;

    const float* WX[3] = {wir, wiz, win};
    const float* WH[3] = {whr, whz, whn};

    // per-thread B base offset (col = o0 + wv*16 + lr owned by this lane)
    const size_t bcolofs = (size_t)u * (IFEAT * OFEAT) + o0 + wv * 16 + lr;

    float rbFa[3][8], rbFb[3][8];              // f32 load double-buffer
    v8s bfQa[3], bfQb[3];                      // bf16 operand queue

#define LOADB(dst, s)                                                        \
    {                                                                        \
        const float* const* W = ((s) < 8) ? WX : WH;                         \
        const size_t boff = bcolofs + (size_t)(((s) & 7) * 4 + lg) * 8 * OFEAT; \
        _Pragma("unroll")                                                    \
        for (int g = 0; g < 3; ++g) {                                        \
            const float* p = W[g] + boff;                                    \
            _Pragma("unroll")                                                \
            for (int j = 0; j < 8; ++j) dst[g][j] = p[j * OFEAT];            \
        }                                                                    \
    }
#define CVTQ(dq, sr)                                                         \
    {                                                                        \
        _Pragma("unroll")                                                    \
        for (int g = 0; g < 3; ++g) dq[g] = pk8(sr[g]);                      \
    }

    // ---- prologue: issue loads(0),(1) first, then stage A + Ht ----
    LOADB(rbFa, 0);
    LOADB(rbFb, 1);
    {
        const int kqA = lane >> 1;             // lane owns k = lane*4..+3
        const int j0  = (lane & 1) * 4;
#pragma unroll
        for (int i = 0; i < 16; ++i) {
            const int row = wv * 16 + i;
            v4f q = *(const v4f*)(x + (size_t)(b0 + row) * (UNITS * IFEAT)
                                    + u * IFEAT + lane * 4);
            uint2 w;
            w.x = pk2(q[0], q[1]);
            w.y = pk2(q[2], q[3]);
            *(uint2*)&As[kqA][(row + kqA) & 127][j0] = w;
        }
    }
    if (t < 32) {
        const float* hp = hinit + u * IFEAT + t * 8;
        v4f q0 = *(const v4f*)hp;
        v4f q1 = *(const v4f*)(hp + 4);
        uint4 w;
        w.x = pk2(q0[0], q0[1]);
        w.y = pk2(q0[2], q0[3]);
        w.z = pk2(q1[0], q1[1]);
        w.w = pk2(q1[2], q1[3]);
        *(uint4*)&Ht[t][0] = w;
    }

    v4f acc[3][8];                             // [gate][mi] x-part
    v4f acch[3];                               // [gate]     h-part (bcast)
#pragma unroll
    for (int g = 0; g < 3; ++g)
#pragma unroll
        for (int mi = 0; mi < 8; ++mi)
            acc[g][mi] = (v4f){0.f, 0.f, 0.f, 0.f};

    __syncthreads();                           // the ONLY barrier
    CVTQ(bfQa, rbFa);                          // cvt(0)

    // ---- K-loop: 16 steps (8 x-phase + 8 h-phase), barrier-free ----
#pragma unroll
    for (int s = 0; s < 16; ++s) {
        // 1) issue loads(s+2) into the f32 buffer freed by cvt(s) last step
        if (s < 14) {
            if (s & 1) { LOADB(rbFb, s + 2); }
            else       { LOADB(rbFa, s + 2); }
        }

        // 2) MFMA(s) — operands were converted at the end of step s-1
        const int kq = (s & 7) * 4 + lg;
        if (s < 8) {
#pragma unroll
            for (int mi = 0; mi < 8; ++mi) {
                v8s a = *(const v8s*)&As[kq][((mi * 16 + lr) + kq) & 127][0];
#pragma unroll
                for (int g = 0; g < 3; ++g) {
                    const v8s bv = (s & 1) ? bfQb[g] : bfQa[g];
                    acc[g][mi] = __builtin_amdgcn_mfma_f32_16x16x32_bf16(
                        a, bv, acc[g][mi], 0, 0, 0);
                }
            }
        } else {
            if (s == 8) {
#pragma unroll
                for (int g = 0; g < 3; ++g) acch[g] = (v4f){0.f, 0.f, 0.f, 0.f};
            }
            v8s a0h = *(const v8s*)&Ht[kq][0];
#pragma unroll
            for (int g = 0; g < 3; ++g) {
                const v8s bv = (s & 1) ? bfQb[g] : bfQa[g];
                acch[g] = __builtin_amdgcn_mfma_f32_16x16x32_bf16(
                    a0h, bv, acch[g], 0, 0, 0);
            }
        }

        // 3) cvt(s+1): vmcnt wait lands ~1.5-2 steps after its loads issued
        if (s < 15) {
            if (s & 1) { CVTQ(bfQa, rbFa); }
            else       { CVTQ(bfQb, rbFb); }
        }
    }
#undef LOADB
#undef CVTQ

    // ---- epilogue: GRU combine ----
    // C layout: col = lane&15, row = (lane>>4)*4 + reg; acch rows identical
    const int o = o0 + wv * 16 + lr;
    const float h0v = hinit[u * OFEAT + o];
    const float hr = acch[0][0];
    const float hz = acch[1][0];
    const float hn = acch[2][0];
#pragma unroll
    for (int mi = 0; mi < 8; ++mi) {
#pragma unroll
        for (int jj = 0; jj < 4; ++jj) {
            const int row = b0 + mi * 16 + lg * 4 + jj;
            const float r = sigmoid_f(acc[0][mi][jj] + hr);
            const float z = sigmoid_f(acc[1][mi][jj] + hz);
            const float n = tanh_f(acc[2][mi][jj] + r * hn);
            out[(size_t)row * (UNITS * OFEAT) + u * OFEAT + o] =
                (1.0f - z) * n + z * h0v;
        }
    }
}

extern "C" void kernel_launch(void* const* d_in, const int* in_sizes, int n_in,
                              void* d_out, int out_size, void* d_ws, size_t ws_size,
                              hipStream_t stream) {
    const float* x     = (const float*)d_in[0];
    const float* w_ir  = (const float*)d_in[1];
    const float* w_iz  = (const float*)d_in[2];
    const float* w_in  = (const float*)d_in[3];
    const float* w_hr  = (const float*)d_in[4];
    const float* w_hz  = (const float*)d_in[5];
    const float* w_hn  = (const float*)d_in[6];
    const float* hinit = (const float*)d_in[7];
    float* out = (float*)d_out;

    gru_fused<<<dim3(256), dim3(512), 0, stream>>>(
        x, w_ir, w_iz, w_in, w_hr, w_hz, w_hn, hinit, out);
}